// Round 4
// baseline (45396.216 us; speedup 1.0000x reference)
//
#include <hip/hip_runtime.h>
#include <cmath>

#define LN 256
#define MM 8
#define HIDN 1024
#define NSTEP 2047
#define NWG 32
#define TPB 256
#define W1R 32      // W1 rows per WG (HID/NWG)
#define GR 8        // dz rows per WG (L/NWG)
#define ZUN (LN+MM) // 264

#define KAPPA 0.65f
#define GAMMA 0.41f
#define TAUC 0.98f
#define INV_HALPHA 3.125f
#define RHOC 0.34f
#define V0C 0.04f
#define ALPHA 0.1f
#define LOG2_1MRHO (-0.5994620717f)

typedef unsigned long long u64;

// ---- LDS layout (floats) ----
#define OFF_W1 0
#define N_W1 (W1R*ZUN)          // 8448  (own 32 W1 rows)
#define OFF_W2 (OFF_W1+N_W1)
#define N_W2 (GR*HIDN)          // 8192  (own 8 W2 ROWS)
#define OFF_A (OFF_W2+N_W2)
#define N_A (GR*LN)             // 2048
#define OFF_B (OFF_A+N_A)
#define N_B (MM*GR*LN)          // 16384
#define OFF_C (OFF_B+N_B)
#define N_C (GR*MM)             // 64
#define OFF_B1 (OFF_C+N_C)
#define N_B1 (W1R)
#define OFF_B2 (OFF_B1+N_B1)
#define N_B2 (GR)
#define OFF_ZU (OFF_B2+N_B2)
#define N_ZU (ZUN)
#define OFF_HF (OFF_ZU+N_ZU)
#define N_HF (HIDN)             // full h vector
#define SMEM_FLOATS (OFF_HF+N_HF) // 36464
#define SMEM_BYTES (SMEM_FLOATS*4) // 145856 <= 160 KiB

// d_ws: hbuf[2][HIDN] u64 at byte 0 (16 KB); dzbuf[2][LN] u64 at 16384 (4 KB).
// Fused word = (epoch<<32)|f32bits. Epoch match => payload valid (8B atomic).
#define WS_DZ_OFF 16384

__global__ void dcm_init(u64* w) {
  for (int i = threadIdx.x; i < 2 * HIDN + 2 * LN; i += 256) w[i] = 0ull;
}

__device__ __forceinline__ u64 fuse(unsigned e, float x) {
  return ((u64)e << 32) | (u64)__float_as_uint(x);
}

__global__ void __launch_bounds__(TPB, 1) dcm_kernel(
    const float* __restrict__ Ag, const float* __restrict__ Bg,
    const float* __restrict__ Cg, const float* __restrict__ W1g,
    const float* __restrict__ b1g, const float* __restrict__ W2g,
    const float* __restrict__ b2g, const float* __restrict__ Ug,
    const float* __restrict__ Tg, float* __restrict__ outg,
    u64* __restrict__ hbuf, u64* __restrict__ dzbuf)
{
  extern __shared__ float sm[];
  const int wg = blockIdx.x, tid = threadIdx.x;
  float* w1s = sm + OFF_W1;
  float* w2s = sm + OFF_W2;
  float* as_ = sm + OFF_A;
  float* bs_ = sm + OFF_B;
  float* cs_ = sm + OFF_C;
  float* b1s = sm + OFF_B1;
  float* b2s = sm + OFF_B2;
  float* zu  = sm + OFF_ZU;
  float* hfull = sm + OFF_HF;

  // ---- stage weights into LDS (once) ----
  for (int i = tid; i < N_W1; i += TPB) {
    int r = i / ZUN, k = i - r * ZUN;
    w1s[i] = W1g[(wg * W1R + r) * ZUN + k];
  }
  for (int i = tid; i < N_W2; i += TPB) {
    int r = i >> 10, k = i & (HIDN - 1);
    w2s[i] = W2g[(wg * GR + r) * HIDN + k];   // own 8 rows of W2
  }
  for (int i = tid; i < N_A; i += TPB) {
    int r = i >> 8, k = i & (LN - 1);
    as_[i] = Ag[(wg * GR + r) * LN + k];
  }
  for (int i = tid; i < N_B; i += TPB) {
    int m = i / (GR * LN); int rem = i - m * GR * LN;
    int r = rem >> 8, k = rem & (LN - 1);
    bs_[i] = Bg[(m * LN + wg * GR + r) * LN + k];
  }
  for (int i = tid; i < N_C; i += TPB) {
    int r = i >> 3, m = i & 7;
    cs_[i] = Cg[(wg * GR + r) * MM + m];
  }
  for (int i = tid; i < N_B1; i += TPB) b1s[i] = b1g[wg * W1R + i];
  for (int i = tid; i < N_B2; i += TPB) b2s[i] = b2g[wg * GR + i];

  // ---- init state (replicated; thread tid owns element l = tid) ----
  float zb = 0.f, sb = 0.f, fb = 1.f, vb = 1.f, qb = 1.f;
  zu[tid] = 0.f;

  if (wg == 0) {  // output row 0
    outg[tid] = 0.f;
    outg[LN + tid] = 0.f;
    outg[2 * LN + tid] = 1.f;
    outg[3 * LN + tid] = 1.f;
    outg[4 * LN + tid] = 1.f;
    outg[(size_t)2048 * 1280 + tid] = 0.f;
  }

  for (int t = 0; t < NSTEP; ++t) {
    float hstep = Tg[t + 1] - Tg[t];
    float zst = zb, sst = sb, fst = fb, vst = vb, qst = qb;
    float kz = 0.f, ks = 0.f, kf = 0.f, kv = 0.f, kq = 0.f;

    float u0r = 0.f, umr = 0.f, u1r = 0.f;
    if (tid < MM) {
      u0r = Ug[(2 * t) * MM + tid];
      umr = Ug[(2 * t + 1) * MM + tid];
      u1r = Ug[(2 * t + 2) * MM + tid];
    }

    for (int st = 0; st < 4; ++st) {
      const int stg = 4 * t + st;
      const unsigned e1 = 2 * (unsigned)stg + 1;
      const unsigned e2 = e1 + 1;
      u64* hb  = hbuf  + (size_t)(stg & 1) * HIDN;
      u64* dzb = dzbuf + (size_t)(stg & 1) * LN;

      if (tid < MM) zu[LN + tid] = (st == 0) ? u0r : (st == 3) ? u1r : umr;
      __syncthreads();                      // (a) zu (z + u) visible

      float uu[MM];
      #pragma unroll
      for (int m = 0; m < MM; ++m) uu[m] = zu[LN + m];

      // ---- phase 1: h rows = tanh(W1 @ zu + b1); publish fused ----
      {
        int row = tid >> 3, sub = tid & 7;
        const float* wrow = w1s + row * ZUN + sub * 33;
        const float* zrow = zu + sub * 33;
        float acc = 0.f;
        #pragma unroll
        for (int j = 0; j < 33; ++j) acc += wrow[j] * zrow[j];
        acc += __shfl_xor(acc, 1);
        acc += __shfl_xor(acc, 2);
        acc += __shfl_xor(acc, 4);
        if (sub == 0) {
          float hv = tanhf(acc + b1s[row]);
          hfull[wg * W1R + row] = hv;       // own slice direct to LDS
          __hip_atomic_store(&hb[wg * W1R + row], fuse(e1, hv),
                             __ATOMIC_RELAXED, __HIP_MEMORY_SCOPE_AGENT);
        }
      }

      // ---- gather h: thread polls 4 consecutive fused words (skip own WG) ----
      if ((tid >> 3) != wg) {
        const int j0 = tid * 4;
        u64 vv[4]; unsigned done = 0u;
        while (done != 0xFu) {
          #pragma unroll
          for (int i = 0; i < 4; ++i)
            if (!(done & (1u << i)))
              vv[i] = __hip_atomic_load(&hb[j0 + i], __ATOMIC_RELAXED,
                                        __HIP_MEMORY_SCOPE_AGENT);
          #pragma unroll
          for (int i = 0; i < 4; ++i)
            if (!(done & (1u << i)))
              if ((unsigned)(vv[i] >> 32) == e1) done |= (1u << i);
        }
        #pragma unroll
        for (int i = 0; i < 4; ++i) hfull[j0 + i] = __uint_as_float((unsigned)vv[i]);
      }
      __syncthreads();                      // (b) hfull complete

      // ---- phase 2: own 8 dz rows exactly; publish fused ----
      {
        int r = tid >> 5, s = tid & 31;
        const float* arow = as_ + r * LN;
        float part = 0.f;
        #pragma unroll
        for (int j = 0; j < 8; ++j) {
          int k = s + 32 * j;
          float w = arow[k];
          #pragma unroll
          for (int m = 0; m < MM; ++m) w += uu[m] * bs_[(m * GR + r) * LN + k];
          part += w * zu[k];
        }
        float w2p = 0.f;
        const float* w2row = w2s + r * HIDN;
        #pragma unroll
        for (int j = 0; j < 32; ++j) w2p += w2row[s + 32 * j] * hfull[s + 32 * j];
        part += ALPHA * w2p;
        part += __shfl_xor(part, 1);
        part += __shfl_xor(part, 2);
        part += __shfl_xor(part, 4);
        part += __shfl_xor(part, 8);
        part += __shfl_xor(part, 16);
        if (s == 0) {
          float cu = 0.f;
          #pragma unroll
          for (int m = 0; m < MM; ++m) cu += cs_[r * MM + m] * uu[m];
          float dzv = part + cu + ALPHA * b2s[r];
          __hip_atomic_store(&dzb[wg * GR + r], fuse(e2, dzv),
                             __ATOMIC_RELAXED, __HIP_MEMORY_SCOPE_AGENT);
        }
      }

      // ---- hemodynamic elementwise (local; overlaps dz store flight) ----
      float ds = zst - KAPPA * sst - GAMMA * (fst - 1.f);
      float df = sst;
      float fv = exp2f(INV_HALPHA * log2f(vst));
      float dv = (fst - fv) / TAUC;
      float E  = 1.f - exp2f(LOG2_1MRHO / fst);
      float dq = (fst * E / RHOC - fv * qst / vst) / TAUC;

      // ---- poll exactly one word: dz for my element ----
      float dz;
      {
        const u64* p = &dzb[tid];
        for (;;) {
          u64 v = __hip_atomic_load(p, __ATOMIC_RELAXED, __HIP_MEMORY_SCOPE_AGENT);
          if ((unsigned)(v >> 32) == e2) { dz = __uint_as_float((unsigned)v); break; }
        }
      }

      float wk = (st == 0 || st == 3) ? 1.f : 2.f;
      kz += wk * dz; ks += wk * ds; kf += wk * df; kv += wk * dv; kq += wk * dq;

      if (st < 3) {
        float c = (st == 2) ? hstep : 0.5f * hstep;
        zst = zb + c * dz; sst = sb + c * ds; fst = fb + c * df;
        vst = vb + c * dv; qst = qb + c * dq;
        zu[tid] = zst;                      // safe: no zu reader between (b) and here
      }
    }

    float h6 = hstep * (1.f / 6.f);
    zb += h6 * kz; sb += h6 * ks; kf *= 1.f; fb += h6 * kf; vb += h6 * kv; qb += h6 * kq;
    zu[tid] = zb;                           // z for next step's k1

    if ((t & (NWG - 1)) == wg) {            // distribute output writes
      size_t ro = (size_t)(t + 1) * 1280;
      outg[ro + tid] = zb;
      outg[ro + LN + tid] = sb;
      outg[ro + 2 * LN + tid] = fb;
      outg[ro + 3 * LN + tid] = vb;
      outg[ro + 4 * LN + tid] = qb;
      float yv = V0C * (2.38f * (1.f - qb) + 2.f * (1.f - qb / vb) + 0.48f * (1.f - vb));
      outg[(size_t)2048 * 1280 + (size_t)(t + 1) * LN + tid] = yv;
    }
  }
}

extern "C" void kernel_launch(void* const* d_in, const int* in_sizes, int n_in,
                              void* d_out, int out_size, void* d_ws, size_t ws_size,
                              hipStream_t stream) {
  const float* Ag  = (const float*)d_in[0];
  const float* Bg  = (const float*)d_in[1];
  const float* Cg  = (const float*)d_in[2];
  const float* W1g = (const float*)d_in[3];
  const float* b1g = (const float*)d_in[4];
  const float* W2g = (const float*)d_in[5];
  const float* b2g = (const float*)d_in[6];
  const float* Ug  = (const float*)d_in[7];
  const float* Tg  = (const float*)d_in[8];
  float* outg = (float*)d_out;

  u64* hbuf  = (u64*)d_ws;
  u64* dzbuf = (u64*)((char*)d_ws + WS_DZ_OFF);

  hipFuncSetAttribute((const void*)dcm_kernel,
                      hipFuncAttributeMaxDynamicSharedMemorySize, SMEM_BYTES);

  hipLaunchKernelGGL(dcm_init, dim3(1), dim3(256), 0, stream, (u64*)d_ws);
  hipLaunchKernelGGL(dcm_kernel, dim3(NWG), dim3(TPB), SMEM_BYTES, stream,
                     Ag, Bg, Cg, W1g, b1g, W2g, b2g, Ug, Tg, outg, hbuf, dzbuf);
}